// Round 12
// baseline (5576.396 us; speedup 1.0000x reference)
//
#include <hip/hip_runtime.h>
#include <hip/hip_fp16.h>

// LSTM B=8192 S=1024 H=256 — round 12: dual unsynchronized wave-groups.
// r7..r11 invariant: wall = MFMA + VALU (serialized) because both waves on a
// SIMD belong to one block-barriered lockstep. Fix: 512-thr block = 2 groups
// of 4 waves (waves i, i+4 share a SIMD => one wave of EACH group per SIMD).
// Quads {B,B+8,+16,+24} share 128 rows; group g runs the r7-proven 2-set x
// 32-row chain for rows [g*64, g*64+64) INDEPENDENTLY: group-local LDS
// split-barrier (ds_add + broadcast spin), per-group flags/pub communities,
// parity-double-buffered LDS h images (own quarter ds_written directly).
// Groups drift into anti-phase (seeded skew): one group's MFMA bursts overlap
// the other's VALU/trans bursts. wfrag 128 regs STATIC-indexed; 8-trans cells.

typedef _Float16 f16x8 __attribute__((ext_vector_type(8)));
typedef float f32x4 __attribute__((ext_vector_type(4)));
typedef unsigned int u32;
typedef unsigned short u16;

#define WINT_OFF 0u
#define W0B_OFF  524288u
#define FLAG_OFF 528384u   // int[256 blocks][2 grp][2 set][16] = 64 KB
#define PUB_OFF  1048576u  // u16 slabs: (((set*2+par)*128+comm)*4+q)*2048 = 8.4 MB

static __device__ __forceinline__ float fast_exp2(float x) {
#if __has_builtin(__builtin_amdgcn_exp2f)
  return __builtin_amdgcn_exp2f(x);
#else
  return exp2f(x);
#endif
}
static __device__ __forceinline__ float fast_rcp(float x) {
#if __has_builtin(__builtin_amdgcn_rcpf)
  return __builtin_amdgcn_rcpf(x);
#else
  return 1.0f / x;
#endif
}
static __device__ __forceinline__ u16 f16b(float f) {
  union { _Float16 h; u16 u; } cv; cv.h = (_Float16)f; return cv.u;
}
static __device__ __forceinline__ float h2f(u16 u) {
  union { u16 u; _Float16 h; } cv; cv.u = u; return (float)cv.h;
}

// Wint[n][k], n = g*256 + j; w0b[n] = packed fp16 {w0, bias}.
__global__ void lstm_prep(const float* __restrict__ Wf, const float* __restrict__ Wi,
                          const float* __restrict__ Wc, const float* __restrict__ Wo,
                          const float* __restrict__ bf_, const float* __restrict__ bi_,
                          const float* __restrict__ bc_, const float* __restrict__ bo_,
                          u16* __restrict__ Wint, u32* __restrict__ w0b) {
  int n = blockIdx.x;       // 0..1023
  int k = threadIdx.x;      // 0..255
  int g = n >> 8, j = n & 255;
  const float* Ws = (g == 0) ? Wf : (g == 1) ? Wi : (g == 2) ? Wc : Wo;
  Wint[n * 256 + k] = f16b(Ws[j * 257 + 1 + k]);
  if (k == 0) {
    const float* bs = (g == 0) ? bf_ : (g == 1) ? bi_ : (g == 2) ? bc_ : bo_;
    w0b[n] = (u32)f16b(Ws[j * 257]) | ((u32)f16b(bs[j]) << 16);
  }
}

// Zero parity-0 pub of both sets (h_0 = 0), flags (64 KB), out = bout.
// pub uint4 ranges: set0/par0 = [0,131072); set1/par0 = [262144,393216).
__global__ void lstm_zero(uint4* __restrict__ pub4, uint4* __restrict__ flags4,
                          float* __restrict__ out, const float* __restrict__ bout) {
  int idx = blockIdx.x * 256 + threadIdx.x;
  uint4 z = uint4{0, 0, 0, 0};
  if (idx < 131072) pub4[idx] = z;
  else if (idx < 262144) pub4[idx + 131072] = z;
  else if (idx < 266240) flags4[idx - 262144] = z;
  else { int o = idx - 266240; if (o < 8192) out[o] = bout[0]; }
}

__global__ __launch_bounds__(512, 2) void lstm_main(
    const u16* __restrict__ Wint, const u32* __restrict__ w0b,
    const float* __restrict__ x, const float* __restrict__ Wout,
    float* __restrict__ out, u16* __restrict__ pub, int* __restrict__ flags) {

  // stg slab index: (((grp*2+s)*2+par)*4+q)*2048 u16  (32 slabs x 4 KB = 128 KB)
  __shared__ __align__(16) u16 stg[32 * 2048];
  __shared__ __align__(16) float lw0f[256], lbsf[256];
  __shared__ u32 gcnt[32];                      // [grp*16]

  const int tid  = threadIdx.x;
  const int wv   = tid >> 6;
  const int grp  = wv >> 2;        // 0: waves 0-3, 1: waves 4-7 (one each/SIMD)
  const int wvl  = wv & 3;
  const int lane = tid & 63;
  const int l15  = lane & 15;
  const int quad = lane >> 4;
  const int B    = blockIdx.x;
  const int qi   = (B >> 3) & 3;                // member in quad
  const int qd   = (B & 7) | ((B >> 5) << 3);   // quad 0..63
  const int b0   = (B & 7) | ((B >> 5) << 5);   // member-0 block id
  const int comm = qd * 2 + grp;                // exchange community 0..127
  const int rowsg = qd * 128 + grp * 64;        // group's 64 rows

  // ---- one-time: W A-fragments (16 j/wave; STATIC reg indices) ----
  f16x8 wfrag[4][8];
#pragma unroll
  for (int g = 0; g < 4; ++g)
#pragma unroll
    for (int ks = 0; ks < 8; ++ks)
      wfrag[g][ks] = *(const f16x8*)(Wint +
          (size_t)(g * 256 + qi * 64 + wvl * 16 + l15) * 256 + ks * 32 + quad * 8);
  if (tid < 256) {
    u32 pk = w0b[(tid >> 6) * 256 + qi * 64 + (tid & 63)];
    lw0f[tid] = h2f((u16)pk);
    lbsf[tid] = h2f((u16)(pk >> 16));
  }
  if (tid < 32) gcnt[tid] = 0;
#pragma unroll
  for (int i = 0; i < 16; ++i) ((uint4*)stg)[tid + i * 512] = uint4{0, 0, 0, 0};

  float cst[2][2][4];   // [s][bt][r]: cell (b = bt*16+l15, j = qi*64+wvl*16+quad*4+r)
#pragma unroll
  for (int s = 0; s < 2; ++s)
#pragma unroll
    for (int bt = 0; bt < 2; ++bt)
#pragma unroll
      for (int r = 0; r < 4; ++r) cst[s][bt][r] = 0.0f;

  const float* xq = x + (size_t)rowsg * 1024;
  float xcur[2][2];
#pragma unroll
  for (int s = 0; s < 2; ++s)
#pragma unroll
    for (int bt = 0; bt < 2; ++bt)
      xcur[s][bt] = xq[(size_t)(s * 32 + bt * 16 + l15) * 1024];

  int* const myfl = flags + (B * 2 + grp) * 2 * 16;   // + s*16
  const int* pfl[3];
#pragma unroll
  for (int d = 0; d < 3; ++d) {
    int pb = b0 + (((qi + d + 1) & 3) << 3);
    pfl[d] = flags + (pb * 2 + grp) * 2 * 16;
  }
  u32* const mycnt = &gcnt[grp * 16];

  __syncthreads();                 // last block-wide barrier
  int barn = 0;
  if (grp == 1) { __builtin_amdgcn_s_sleep(15); __builtin_amdgcn_s_sleep(8); }

// SUBPHASE(S): one step of set S at time t for this group.
#define SUBPHASE(S)                                                               \
  {                                                                               \
    const int par = t & 1;                                                        \
    /* acc init = x*w0 + bias; x prefetch early */                                \
    f32x4 acc[4][2];                                                              \
    _Pragma("unroll")                                                             \
    for (int g = 0; g < 4; ++g) {                                                 \
      f32x4 w4 = *(const f32x4*)&lw0f[g * 64 + wvl * 16 + quad * 4];              \
      f32x4 b4 = *(const f32x4*)&lbsf[g * 64 + wvl * 16 + quad * 4];              \
      _Pragma("unroll")                                                           \
      for (int r = 0; r < 4; ++r) {                                               \
        acc[g][0][r] = xcur[S][0] * w4[r] + b4[r];                                \
        acc[g][1][r] = xcur[S][1] * w4[r] + b4[r];                                \
      }                                                                           \
    }                                                                             \
    xcur[S][0] = xq[(size_t)((S) * 32 + l15) * 1024 + ((t + 1) & 1023)];          \
    xcur[S][1] = xq[(size_t)((S) * 32 + 16 + l15) * 1024 + ((t + 1) & 1023)];     \
    /* K-loop over 256 k (quarter-major slabs, parity par) */                     \
    const u16* img = stg + (size_t)(((grp * 2 + (S)) * 2 + par) * 4) * 2048;      \
    _Pragma("unroll")                                                             \
    for (int ks = 0; ks < 8; ++ks) {                                              \
      f16x8 bfr[2];                                                               \
      _Pragma("unroll")                                                           \
      for (int bt = 0; bt < 2; ++bt) {                                            \
        int b = bt * 16 + l15;                                                    \
        int c = (((ks & 1) * 4 + quad)) ^ (b & 7);                                \
        bfr[bt] = *(const f16x8*)(img + (ks >> 1) * 2048 + b * 64 + c * 8);       \
      }                                                                           \
      _Pragma("unroll")                                                           \
      for (int g = 0; g < 4; ++g)                                                 \
        _Pragma("unroll")                                                         \
        for (int bt = 0; bt < 2; ++bt)                                            \
          acc[g][bt] = __builtin_amdgcn_mfma_f32_16x16x32_f16(                    \
              wfrag[g][ks], bfr[bt], acc[g][bt], 0, 0, 0);                        \
    }                                                                             \
    /* poll + DMA other set's h(tn) into its parity buffer (3 chunks/wave) */     \
    const int tn = ((S) == 0) ? t : t + 1;                                        \
    if (tn < 1024) {                                                              \
      _Pragma("unroll")                                                           \
      for (int d = 0; d < 3; ++d)                                                 \
        while (__hip_atomic_load(pfl[d] + (1 - (S)) * 16, __ATOMIC_RELAXED,       \
                                 __HIP_MEMORY_SCOPE_AGENT) < tn)                  \
          __builtin_amdgcn_s_sleep(1);                                            \
      _Pragma("unroll")                                                           \
      for (int i = 0; i < 3; ++i) {                                               \
        int c = wvl * 3 + i, pi = c >> 2, part = c & 3;                           \
        int qq = (qi + pi + 1) & 3;                                               \
        const u16* src = pub +                                                    \
            (size_t)((((1 - (S)) * 2 + (tn & 1)) * 128 + comm) * 4 + qq) * 2048   \
            + part * 512 + lane * 8;                                              \
        __builtin_amdgcn_global_load_lds(                                         \
            (const __attribute__((address_space(1))) u32*)src,                    \
            (__attribute__((address_space(3))) u32*)(stg +                        \
                (size_t)(((grp * 2 + (1 - (S))) * 2 + (tn & 1)) * 4 + qq) * 2048  \
                + part * 512),                                                    \
            16, 0, 0);                                                            \
      }                                                                           \
    }                                                                             \
    /* elementwise (8-trans cells) + publish global + ds_write own slab */        \
    {                                                                             \
      const int po = (t + 1) & 1;                                                 \
      u16* pbS = pub + (size_t)((((S) * 2 + po) * 128 + comm) * 4 + qi) * 2048;   \
      u16* lsS = stg + (size_t)(((grp * 2 + (S)) * 2 + po) * 4 + qi) * 2048;      \
      _Pragma("unroll")                                                           \
      for (int bt = 0; bt < 2; ++bt) {                                            \
        int b = bt * 16 + l15;                                                    \
        float h4[4];                                                              \
        _Pragma("unroll")                                                         \
        for (int r = 0; r < 4; ++r) {                                             \
          float fg = acc[0][bt][r], ig = acc[1][bt][r];                           \
          float cg = acc[2][bt][r], og = acc[3][bt][r];                           \
          float ef = fast_exp2(-1.44269504f * fg);                                \
          float ei = fast_exp2(-1.44269504f * ig);                                \
          float eg = fast_exp2(2.88539008f * cg);                                 \
          float eo = fast_exp2(-1.44269504f * og);                                \
          float c_ = cst[S][bt][r] * fast_rcp(1.0f + ef) +                        \
                     (eg - 1.0f) * fast_rcp((1.0f + ei) * (eg + 1.0f));           \
          cst[S][bt][r] = c_;                                                     \
          float ec = fast_exp2(2.88539008f * c_);                                 \
          h4[r] = (ec - 1.0f) * fast_rcp((1.0f + eo) * (ec + 1.0f));              \
        }                                                                         \
        u32 lo = (u32)f16b(h4[0]) | ((u32)f16b(h4[1]) << 16);                     \
        u32 hi = (u32)f16b(h4[2]) | ((u32)f16b(h4[3]) << 16);                     \
        int off = b * 64 + (((wvl * 2 + (quad >> 1)) ^ (b & 7)) * 8) +            \
                  (quad & 1) * 4;                                                 \
        *(uint2*)(pbS + off) = uint2{lo, hi};                                     \
        *(uint2*)(lsS + off) = uint2{lo, hi};                                     \
      }                                                                           \
    }                                                                             \
    /* group split-barrier: drain this wave, add, spin (broadcast read) */        \
    __builtin_amdgcn_s_waitcnt(0x0070); /* vmcnt(0) + lgkmcnt(0) */               \
    if (lane == 0)                                                                \
      __hip_atomic_fetch_add(mycnt, 1u, __ATOMIC_RELEASE,                         \
                             __HIP_MEMORY_SCOPE_WORKGROUP);                       \
    barn += 4;                                                                    \
    while ((int)__hip_atomic_load(mycnt, __ATOMIC_ACQUIRE,                        \
                                  __HIP_MEMORY_SCOPE_WORKGROUP) < barn)           \
      __builtin_amdgcn_s_sleep(1);                                                \
    if (wvl == 0 && lane == 0)                                                    \
      __hip_atomic_store(myfl + (S) * 16, t + 1, __ATOMIC_RELAXED,                \
                         __HIP_MEMORY_SCOPE_AGENT);                               \
  }

#pragma unroll 1
  for (int t = 0; t < 1024; ++t) {
    SUBPHASE(0);
    SUBPHASE(1);
  }
#undef SUBPHASE

  // ---- out[row] += (own j-quarter of h(1024)) . Wout  (out pre-set to bout) ----
  // h_s(1024) own slab at parity 0 (written by EW at t=1023).
  {
    int tg = wvl * 64 + lane;          // 0..255 within group
    int row = tg >> 2, p = tg & 3;     // row 0..63, 4 threads/row
    int s = row >> 5, b = row & 31;
    const u16* img = stg + (size_t)(((grp * 2 + s) * 2 + 0) * 4 + qi) * 2048;
    float a = 0.0f;
#pragma unroll
    for (int i = 0; i < 2; ++i) {
      int c = p + i * 4;
      f16x8 hv = *(const f16x8*)(img + b * 64 + ((c ^ (b & 7)) * 8));
#pragma unroll
      for (int e = 0; e < 8; ++e) a += (float)hv[e] * Wout[qi * 64 + c * 8 + e];
    }
    a += __shfl_xor(a, 1);
    a += __shfl_xor(a, 2);
    if (p == 0) atomicAdd(&out[rowsg + row], a);
  }
}

extern "C" void kernel_launch(void* const* d_in, const int* in_sizes, int n_in,
                              void* d_out, int out_size, void* d_ws, size_t ws_size,
                              hipStream_t stream) {
  const float* x    = (const float*)d_in[0];
  const float* Wf   = (const float*)d_in[1];
  const float* bf_  = (const float*)d_in[2];
  const float* Wi   = (const float*)d_in[3];
  const float* bi_  = (const float*)d_in[4];
  const float* Wc   = (const float*)d_in[5];
  const float* bc_  = (const float*)d_in[6];
  const float* Wo   = (const float*)d_in[7];
  const float* bo_  = (const float*)d_in[8];
  const float* Wout = (const float*)d_in[9];
  const float* bout = (const float*)d_in[10];

  u16* Wint  = (u16*)((char*)d_ws + WINT_OFF);
  u32* w0b   = (u32*)((char*)d_ws + W0B_OFF);
  int* flags = (int*)((char*)d_ws + FLAG_OFF);
  u16* pub   = (u16*)((char*)d_ws + PUB_OFF);

  lstm_prep<<<1024, 256, 0, stream>>>(Wf, Wi, Wc, Wo, bf_, bi_, bc_, bo_, Wint, w0b);
  lstm_zero<<<1072, 256, 0, stream>>>((uint4*)pub, (uint4*)flags, (float*)d_out, bout);
  lstm_main<<<256, 512, 0, stream>>>(Wint, w0b, x, Wout, (float*)d_out, pub, flags);
}